// Round 13
// baseline (415.927 us; speedup 1.0000x reference)
//
#include <hip/hip_runtime.h>

#define AS1 __attribute__((address_space(1)))
#define AS3 __attribute__((address_space(3)))

typedef unsigned short u16;
typedef short s16x8 __attribute__((ext_vector_type(8)));
typedef float f32x4 __attribute__((ext_vector_type(4)));

__device__ __forceinline__ float bf2f(u16 u) {
    union { unsigned u; float f; } v; v.u = ((unsigned)u) << 16; return v.f;
}
__device__ __forceinline__ u16 f2bf(float f) {
    union { float f; unsigned u; } v; v.f = f;
    unsigned u = v.u;
    return (u16)((u + 0x7FFFu + ((u >> 16) & 1u)) >> 16);
}

__device__ __forceinline__ void gload16(const void* g, void* l) {
    __builtin_amdgcn_global_load_lds((const AS1 void*)g, (AS3 void*)l, 16, 0, 0);
}

#define MFMA16(a, b, c) __builtin_amdgcn_mfma_f32_16x16x32_bf16(a, b, c, 0, 0, 0)

// ---------------------------------------------------------------- transpose+cvt
__global__ __launch_bounds__(256) void transpose_bf16(
    const float* __restrict__ src, u16* __restrict__ dst, int R, int C)
{
    __shared__ float t[32][33];
    const int tx = threadIdx.x, ty = threadIdx.y;
    const int r0 = blockIdx.x * 32, c0 = blockIdx.y * 32;
#pragma unroll
    for (int i = 0; i < 4; i++)
        t[ty + i * 8][tx] = src[(size_t)(r0 + ty + i * 8) * C + c0 + tx];
    __syncthreads();
#pragma unroll
    for (int i = 0; i < 4; i++)
        dst[(size_t)(c0 + ty + i * 8) * R + r0 + tx] = f2bf(t[tx][ty + i * 8]);
}

// ---------------------------------------------------------------- layernorm -> bf16
__global__ __launch_bounds__(256) void ln_bf16(
    const float* __restrict__ x, const float* __restrict__ w,
    const float* __restrict__ b, u16* __restrict__ out)
{
    __shared__ float red[8];
    const int row = blockIdx.x;
    const int tid = threadIdx.x;
    const size_t base = (size_t)row * 1024 + tid * 4;
    const float4 xv = *(const float4*)&x[base];
    float s = xv.x + xv.y + xv.z + xv.w;
    float q = xv.x * xv.x + xv.y * xv.y + xv.z * xv.z + xv.w * xv.w;
#pragma unroll
    for (int m = 1; m < 64; m <<= 1) { s += __shfl_xor(s, m); q += __shfl_xor(q, m); }
    if ((tid & 63) == 0) { red[tid >> 6] = s; red[4 + (tid >> 6)] = q; }
    __syncthreads();
    s = red[0] + red[1] + red[2] + red[3];
    q = red[4] + red[5] + red[6] + red[7];
    const float mu = s * (1.f / 1024.f);
    const float var = q * (1.f / 1024.f) - mu * mu;
    const float rs = rsqrtf(var + 1e-5f);
    const float4 wv = *(const float4*)&w[tid * 4];
    const float4 bv = *(const float4*)&b[tid * 4];
    uint2 ov;
    ov.x = (unsigned)f2bf((xv.x - mu) * rs * wv.x + bv.x) |
           ((unsigned)f2bf((xv.y - mu) * rs * wv.y + bv.y) << 16);
    ov.y = (unsigned)f2bf((xv.z - mu) * rs * wv.z + bv.z) |
           ((unsigned)f2bf((xv.w - mu) * rs * wv.w + bv.w) << 16);
    *(uint2*)&out[base] = ov;
}

// ---------------------------------------------------------------- 128x64 GEMM, 4 waves (K=1024 shapes)
// wave = 64x32 (4x2 frags, 32 AGPR acc -> ~58% occupancy). BK=64, single-buffer 24 KiB LDS.
// B^T input. EP: 0 = QKVG split; 1 = bf16 gelu(acc+bias)
template <int EPX>
__global__ __launch_bounds__(256, 5) void gemmL(
    const u16* __restrict__ A, const u16* __restrict__ BT,
    float* __restrict__ Cf, u16* __restrict__ Cb,
    const float* __restrict__ bias, int M, int N, int K)
{
    __shared__ u16 As[128 * 64];   // 16 KiB
    __shared__ u16 Bs[64 * 64];    // 8 KiB
    const int tid = threadIdx.x;
    const int w = tid >> 6, l = tid & 63;
    const int tm = blockIdx.x * 128, tn = blockIdx.y * 64;
    const int wr = w >> 1, wc = w & 1;

    const int srow = l >> 3;
    const int sg = ((l & 7) ^ (srow & 7)) * 8;
    int aSb[4], bSb[2];
#pragma unroll
    for (int j = 0; j < 4; j++)
        aSb[j] = (tm + w * 32 + j * 8 + srow) * K + sg;
#pragma unroll
    for (int j = 0; j < 2; j++)
        bSb[j] = (tn + w * 16 + j * 8 + srow) * K + sg;

    const int fr = l & 15, g0 = l >> 4, key = l & 7;
    const int arb = (wr * 64 + fr) * 64;
    const int brb = (wc * 32 + fr) * 64;

    f32x4 acc[4][2] = {};

#pragma unroll
    for (int j = 0; j < 4; j++) gload16(&A[aSb[j]], &As[(w * 32 + j * 8) * 64]);
#pragma unroll
    for (int j = 0; j < 2; j++) gload16(&BT[bSb[j]], &Bs[(w * 16 + j * 8) * 64]);

    const int NT = K >> 6;
    for (int t = 0; t < NT; ++t) {
        __syncthreads();
#pragma unroll
        for (int ks = 0; ks < 2; ks++) {
            const int g = ((ks * 4 + g0) ^ key) * 8;
            s16x8 b0 = *(const s16x8*)&Bs[brb + g];
            s16x8 b1 = *(const s16x8*)&Bs[brb + 16 * 64 + g];
            s16x8 a0 = *(const s16x8*)&As[arb + g];
            s16x8 a1 = *(const s16x8*)&As[arb + 16 * 64 + g];
            s16x8 a2 = *(const s16x8*)&As[arb + 32 * 64 + g];
            s16x8 a3 = *(const s16x8*)&As[arb + 48 * 64 + g];
            acc[0][0] = MFMA16(a0, b0, acc[0][0]);
            acc[0][1] = MFMA16(a0, b1, acc[0][1]);
            acc[1][0] = MFMA16(a1, b0, acc[1][0]);
            acc[1][1] = MFMA16(a1, b1, acc[1][1]);
            acc[2][0] = MFMA16(a2, b0, acc[2][0]);
            acc[2][1] = MFMA16(a2, b1, acc[2][1]);
            acc[3][0] = MFMA16(a3, b0, acc[3][0]);
            acc[3][1] = MFMA16(a3, b1, acc[3][1]);
        }
        if (t + 1 < NT) {
            __syncthreads();
            const int k0 = (t + 1) * 64;
#pragma unroll
            for (int j = 0; j < 4; j++) gload16(&A[aSb[j] + k0], &As[(w * 32 + j * 8) * 64]);
#pragma unroll
            for (int j = 0; j < 2; j++) gload16(&BT[bSb[j] + k0], &Bs[(w * 16 + j * 8) * 64]);
        }
    }

    const int erow0 = tm + wr * 64 + (l >> 4) * 4;
    const int ecol0 = tn + wc * 32 + (l & 15);
#pragma unroll
    for (int i = 0; i < 4; i++) {
#pragma unroll
        for (int j = 0; j < 2; j++) {
            const int col = ecol0 + j * 16;
#pragma unroll
            for (int r = 0; r < 4; r++) {
                const int row = erow0 + i * 16 + r;
                const float v = acc[i][j][r];
                if (EPX == 0) {
                    if (col < 3072) Cb[(size_t)row * 3072 + col] = f2bf(v);
                    else            Cf[(size_t)row * 1024 + (col - 3072)] = v;
                } else {
                    const float u2 = v + bias[col];
                    Cb[(size_t)row * N + col] =
                        f2bf(0.5f * u2 * (1.f + erff(u2 * 0.70710678118654752f)));
                }
            }
        }
    }
}

// ---------------------------------------------------------------- 256x128 GEMM (Wo, FFN2 — R9 config)
// wave = 64x64 (4x4 frags). BK=64, single-buffer 48 KiB LDS.
// EP: 2 = f32 +resid; 4 = f32 +bias+resid
template <int EPX>
__global__ __launch_bounds__(512) void gemmM(
    const u16* __restrict__ A, const u16* __restrict__ BT,
    float* __restrict__ Cf,
    const float* __restrict__ bias, const float* __restrict__ resid,
    int M, int N, int K)
{
    __shared__ u16 As[256 * 64];
    __shared__ u16 Bs[128 * 64];
    const int tid = threadIdx.x;
    const int w = tid >> 6, l = tid & 63;
    const int tm = blockIdx.x * 256, tn = blockIdx.y * 128;
    const int wr = w >> 1, wc = w & 1;

    const int srow = l >> 3;
    const int sg = ((l & 7) ^ (srow & 7)) * 8;
    size_t aSb[4], bSb[2];
#pragma unroll
    for (int j = 0; j < 4; j++)
        aSb[j] = (size_t)(tm + w * 32 + j * 8 + srow) * K + sg;
#pragma unroll
    for (int j = 0; j < 2; j++)
        bSb[j] = (size_t)(tn + w * 16 + j * 8 + srow) * K + sg;

    const int fr = l & 15, g0 = l >> 4, key = l & 7;
    int aoff[4][2], boff[4][2];
#pragma unroll
    for (int f = 0; f < 4; f++)
#pragma unroll
        for (int ks = 0; ks < 2; ks++) {
            const int g = (((ks * 4 + g0)) ^ key) * 8;
            aoff[f][ks] = (wr * 64 + f * 16 + fr) * 64 + g;
            boff[f][ks] = (wc * 64 + f * 16 + fr) * 64 + g;
        }

    f32x4 acc[4][4] = {};

#pragma unroll
    for (int j = 0; j < 4; j++) gload16(&A[aSb[j]], &As[(w * 32 + j * 8) * 64]);
#pragma unroll
    for (int j = 0; j < 2; j++) gload16(&BT[bSb[j]], &Bs[(w * 16 + j * 8) * 64]);

    const int NT = K >> 6;
    for (int t = 0; t < NT; ++t) {
        __syncthreads();
#pragma unroll
        for (int ks = 0; ks < 2; ks++) {
            s16x8 a[4], b[4];
#pragma unroll
            for (int f = 0; f < 4; f++) {
                a[f] = *(const s16x8*)&As[aoff[f][ks]];
                b[f] = *(const s16x8*)&Bs[boff[f][ks]];
            }
#pragma unroll
            for (int i = 0; i < 4; i++)
#pragma unroll
                for (int j = 0; j < 4; j++)
                    acc[i][j] = MFMA16(a[i], b[j], acc[i][j]);
        }
        if (t + 1 < NT) {
            __syncthreads();
            const int k0 = (t + 1) * 64;
#pragma unroll
            for (int j = 0; j < 4; j++) gload16(&A[aSb[j] + k0], &As[(w * 32 + j * 8) * 64]);
#pragma unroll
            for (int j = 0; j < 2; j++) gload16(&BT[bSb[j] + k0], &Bs[(w * 16 + j * 8) * 64]);
        }
    }

    const int erow0 = tm + wr * 64 + (l >> 4) * 4;
    const int ecol0 = tn + wc * 64 + (l & 15);
#pragma unroll
    for (int i = 0; i < 4; i++) {
#pragma unroll
        for (int j = 0; j < 4; j++) {
            const int col = ecol0 + j * 16;
#pragma unroll
            for (int r = 0; r < 4; r++) {
                const int row = erow0 + i * 16 + r;
                const float v = acc[i][j][r];
                const size_t idx = (size_t)row * N + col;
                if (EPX == 2) Cf[idx] = v + resid[idx];
                else          Cf[idx] = v + bias[col] + resid[idx];
            }
        }
    }
}

// ---------------------------------------------------------------- GLA phase A (MFMA)
#define TP 72
#define LP 65
__global__ __launch_bounds__(256) void gla_a(
    const u16* __restrict__ qkv,
    const float* __restrict__ g,
    const float* __restrict__ bg,
    u16* __restrict__ qdec,
    u16* __restrict__ kvT,
    float* __restrict__ cdec,
    u16* __restrict__ ointra)
{
    __shared__ u16 Qh[64 * TP];
    __shared__ u16 Kh[64 * TP];
    __shared__ u16 VT[64 * TP];
    __shared__ float L[64 * LP];
    __shared__ float lm[64], nq[64], nk[64];

    const int bid = blockIdx.x;
    const int bh = bid >> 6, ck = bid & 63;
    const int b = bh >> 4, h = bh & 15;
    const int tok0 = b * 4096 + ck * 64;
    const int tid = threadIdx.x;
    const int w = tid >> 6, l = tid & 63;

#pragma unroll
    for (int pass = 0; pass < 2; pass++) {
        const int c = (tid >> 3) + pass * 32;
        const int col = (tid & 7) * 8;
        const size_t rb = (size_t)(tok0 + c) * 3072 + h * 64 + col;
        uint4 qv = *(const uint4*)&qkv[rb];
        uint4 kv_ = *(const uint4*)&qkv[rb + 1024];
        uint4 vv = *(const uint4*)&qkv[rb + 2048];
        *(uint4*)&Qh[c * TP + col] = qv;
        *(uint4*)&Kh[c * TP + col] = kv_;
        const u16* va = (const u16*)&vv;
#pragma unroll
        for (int j = 0; j < 8; j++) VT[(col + j) * TP + c] = va[j];
    }
#pragma unroll
    for (int pass = 0; pass < 4; pass++) {
        const int c = (tid >> 4) + pass * 16;
        const int col = (tid & 15) * 4;
        float4 gv = *(const float4*)&g[(size_t)(tok0 + c) * 1024 + h * 64 + col];
        float4 bgv = *(const float4*)&bg[h * 64 + col];
        const float* ga = (const float*)&gv;
        const float* ba = (const float*)&bgv;
#pragma unroll
        for (int i = 0; i < 4; i++) {
            const float z = ga[i] + ba[i];
            const float al = 1.f / (1.f + __expf(-z));
            L[c * LP + col + i] = __logf(fmaxf(al, 1e-6f));
        }
    }
    __syncthreads();

    {
        const int d = tid >> 2, qq = tid & 3;
        float vals[16];
#pragma unroll
        for (int i = 0; i < 16; i++) vals[i] = L[(qq * 16 + i) * LP + d];
        float s = 0.f;
#pragma unroll
        for (int i = 0; i < 16; i++) { s += vals[i]; vals[i] = s; }
        float sum = s;
        float u1 = __shfl_up(sum, 1, 4); if (qq >= 1) sum += u1;
        float u2 = __shfl_up(sum, 2, 4); if (qq >= 2) sum += u2;
        const float excl = sum - s;
#pragma unroll
        for (int i = 0; i < 16; i++) L[(qq * 16 + i) * LP + d] = vals[i] + excl;
        if (qq == 3) cdec[((size_t)bh * 64 + ck) * 64 + d] = __expf(sum);
    }
    __syncthreads();

    {
        const int c = tid >> 2, qq = tid & 3;
        float sl = 0.f, sq = 0.f, sk = 0.f;
        uint4 qa = *(const uint4*)&Qh[c * TP + qq * 16];
        uint4 qb = *(const uint4*)&Qh[c * TP + qq * 16 + 8];
        uint4 ka = *(const uint4*)&Kh[c * TP + qq * 16];
        uint4 kb = *(const uint4*)&Kh[c * TP + qq * 16 + 8];
        const u16* qu = (const u16*)&qa; const u16* qu2 = (const u16*)&qb;
        const u16* ku = (const u16*)&ka; const u16* ku2 = (const u16*)&kb;
#pragma unroll
        for (int i = 0; i < 8; i++) {
            float q1 = bf2f(qu[i]), q2 = bf2f(qu2[i]);
            float k1 = bf2f(ku[i]), k2 = bf2f(ku2[i]);
            sq += q1 * q1 + q2 * q2;
            sk += k1 * k1 + k2 * k2;
        }
#pragma unroll
        for (int i = 0; i < 16; i++) sl += L[c * LP + qq * 16 + i];
        sl += __shfl_xor(sl, 1); sl += __shfl_xor(sl, 2);
        sq += __shfl_xor(sq, 1); sq += __shfl_xor(sq, 2);
        sk += __shfl_xor(sk, 1); sk += __shfl_xor(sk, 2);
        if (qq == 0) {
            lm[c] = sl * (1.f / 64.f);
            nq[c] = 1.f / fmaxf(sqrtf(sq), 1e-12f);
            nk[c] = 1.f / fmaxf(sqrtf(sk), 1e-12f);
        }
    }
    __syncthreads();

    u16 kdt[16];
    {
        const int c = tid >> 2, qq = tid & 3;
        const float qn = nq[c], kn = nk[c];
        uint4 qa = *(const uint4*)&Qh[c * TP + qq * 16];
        uint4 qb = *(const uint4*)&Qh[c * TP + qq * 16 + 8];
        uint4 ka = *(const uint4*)&Kh[c * TP + qq * 16];
        uint4 kb = *(const uint4*)&Kh[c * TP + qq * 16 + 8];
        u16* qu = (u16*)&qa; u16* qu2 = (u16*)&qb;
        u16* ku = (u16*)&ka; u16* ku2 = (u16*)&kb;
        float Lc[16], Le[16];
#pragma unroll
        for (int i = 0; i < 16; i++) {
            Lc[i] = L[c * LP + qq * 16 + i];
            Le[i] = L[63 * LP + qq * 16 + i];
        }
        unsigned pk[8];
#pragma unroll
        for (int i = 0; i < 8; i++) {
            float qh1 = bf2f(qu[i]) * qn;  qu[i] = f2bf(qh1);
            float qh2 = bf2f(qu2[i]) * qn; qu2[i] = f2bf(qh2);
            float kh1 = bf2f(ku[i]) * kn;  ku[i] = f2bf(kh1);
            float kh2 = bf2f(ku2[i]) * kn; ku2[i] = f2bf(kh2);
            kdt[i]     = f2bf(kh1 * __expf(Le[i] - Lc[i]));
            kdt[i + 8] = f2bf(kh2 * __expf(Le[i + 8] - Lc[i + 8]));
        }
#pragma unroll
        for (int i = 0; i < 4; i++) {
            pk[i] = (unsigned)f2bf(bf2f(qu[2 * i]) * __expf(Lc[2 * i])) |
                    ((unsigned)f2bf(bf2f(qu[2 * i + 1]) * __expf(Lc[2 * i + 1])) << 16);
            pk[4 + i] = (unsigned)f2bf(bf2f(qu2[2 * i]) * __expf(Lc[8 + 2 * i])) |
                        ((unsigned)f2bf(bf2f(qu2[2 * i + 1]) * __expf(Lc[8 + 2 * i + 1])) << 16);
        }
        *(uint4*)&Qh[c * TP + qq * 16] = qa;
        *(uint4*)&Qh[c * TP + qq * 16 + 8] = qb;
        *(uint4*)&Kh[c * TP + qq * 16] = ka;
        *(uint4*)&Kh[c * TP + qq * 16 + 8] = kb;
        u16* qrow = &qdec[((size_t)bh * 4096 + ck * 64 + c) * 64 + qq * 16];
        *(uint4*)&qrow[0] = *(const uint4*)&pk[0];
        *(uint4*)&qrow[8] = *(const uint4*)&pk[4];
    }
    __syncthreads();

    u16* KDT = (u16*)L;
    {
        const int c = tid >> 2, qq = tid & 3;
#pragma unroll
        for (int i = 0; i < 16; i++) KDT[(qq * 16 + i) * TP + c] = kdt[i];
    }
    const int fr = l & 15;
    const int kk = (l >> 4) * 8;
    f32x4 accS[4] = {};
#pragma unroll
    for (int ks = 0; ks < 2; ks++) {
        s16x8 af = *(const s16x8*)&Qh[(w * 16 + fr) * TP + ks * 32 + kk];
#pragma unroll
        for (int j = 0; j < 4; j++) {
            s16x8 bf = *(const s16x8*)&Kh[(j * 16 + fr) * TP + ks * 32 + kk];
            accS[j] = MFMA16(af, bf, accS[j]);
        }
    }
    __syncthreads();

    {
        const int erow = w * 16 + (l >> 4) * 4;
#pragma unroll
        for (int j = 0; j < 4; j++) {
            const int mm = j * 16 + (l & 15);
            const float lmm = lm[mm];
#pragma unroll
            for (int r = 0; r < 4; r++) {
                const int cc = erow + r;
                const float wgt = (mm <= cc) ? __expf(lm[cc] - lmm) : 0.f;
                Qh[cc * TP + mm] = f2bf(accS[j][r] * wgt);
            }
        }
    }
    __syncthreads();

    f32x4 accO[4] = {};
    f32x4 accK[4] = {};
#pragma unroll
    for (int ks = 0; ks < 2; ks++) {
        s16x8 aAt = *(const s16x8*)&Qh[(w * 16 + fr) * TP + ks * 32 + kk];
        s16x8 aVt = *(const s16x8*)&VT[(w * 16 + fr) * TP + ks * 32 + kk];
#pragma unroll
        for (int j = 0; j < 4; j++) {
            s16x8 bVt = *(const s16x8*)&VT[(j * 16 + fr) * TP + ks * 32 + kk];
            s16x8 bKd = *(const s16x8*)&KDT[(j * 16 + fr) * TP + ks * 32 + kk];
            accO[j] = MFMA16(aAt, bVt, accO[j]);
            accK[j] = MFMA16(aVt, bKd, accK[j]);
        }
    }
    {
        const int erow = w * 16 + (l >> 4) * 4;
#pragma unroll
        for (int j = 0; j < 4; j++) {
            const int col = j * 16 + (l & 15);
#pragma unroll
            for (int r = 0; r < 4; r++) {
                const int row = erow + r;
                ointra[((size_t)bh * 4096 + ck * 64 + row) * 64 + col] = f2bf(accO[j][r]);
                kvT[(((size_t)bh * 64 + ck) * 64 + row) * 64 + col] = f2bf(accK[j][r]);
            }
        }
    }
}

// ---------------------------------------------------------------- elementwise chunk scan
__global__ __launch_bounds__(256) void gla_scan(
    const u16* __restrict__ kvT, const float* __restrict__ cdec,
    u16* __restrict__ ST)
{
    const int bh = blockIdx.x >> 4;
    const int de = (blockIdx.x & 15) * 256 + threadIdx.x;
    const int d = de & 63;
    float s = 0.f;
    const size_t base = (size_t)bh * 64 * 4096 + de;
    const size_t cb = (size_t)bh * 4096 + d;
    for (int t = 0; t < 64; t++) {
        ST[base + (size_t)t * 4096] = f2bf(s);
        s = s * cdec[cb + (size_t)t * 64] + bf2f(kvT[base + (size_t)t * 4096]);
    }
}

// ---------------------------------------------------------------- GLA phase B (MFMA)
__global__ __launch_bounds__(256) void gla_b(
    const u16* __restrict__ qdec, const u16* __restrict__ ST,
    const u16* __restrict__ ointra, u16* __restrict__ obf)
{
    __shared__ u16 Qd[64 * TP];
    __shared__ u16 Sd[64 * TP];
    const int bid = blockIdx.x;
    const int bh = bid >> 6, ck = bid & 63;
    const int b = bh >> 4, h = bh & 15;
    const int tid = threadIdx.x;
    const int w = tid >> 6, l = tid & 63;
#pragma unroll
    for (int pass = 0; pass < 2; pass++) {
        const int r = (tid >> 3) + pass * 32;
        const int col = (tid & 7) * 8;
        *(uint4*)&Qd[r * TP + col] =
            *(const uint4*)&qdec[((size_t)bh * 4096 + ck * 64 + r) * 64 + col];
        *(uint4*)&Sd[r * TP + col] =
            *(const uint4*)&ST[(((size_t)bh * 64 + ck) * 64 + r) * 64 + col];
    }
    __syncthreads();
    const int fr = l & 15;
    const int kk = (l >> 4) * 8;
    f32x4 acc[4] = {};
#pragma unroll
    for (int ks = 0; ks < 2; ks++) {
        s16x8 af = *(const s16x8*)&Qd[(w * 16 + fr) * TP + ks * 32 + kk];
#pragma unroll
        for (int j = 0; j < 4; j++) {
            s16x8 bf = *(const s16x8*)&Sd[(j * 16 + fr) * TP + ks * 32 + kk];
            acc[j] = MFMA16(af, bf, acc[j]);
        }
    }
    const int erow = w * 16 + (l >> 4) * 4;
#pragma unroll
    for (int j = 0; j < 4; j++) {
        const int e = j * 16 + (l & 15);
#pragma unroll
        for (int r = 0; r < 4; r++) {
            const int cc = erow + r;
            const size_t ia = ((size_t)bh * 4096 + ck * 64 + cc) * 64 + e;
            const float v = acc[j][r] + bf2f(ointra[ia]);
            obf[(size_t)(b * 4096 + ck * 64 + cc) * 1024 + h * 64 + e] = f2bf(v);
        }
    }
}

__global__ void fill_sentinel(float* out, int n) {
    int i = blockIdx.x * 256 + threadIdx.x;
    if (i < n) out[i] = 12345.0f;
}

// ---------------------------------------------------------------- host launcher
extern "C" void kernel_launch(void* const* d_in, const int* in_sizes, int n_in,
                              void* d_out, int out_size, void* d_ws, size_t ws_size,
                              hipStream_t stream)
{
    const float* x    = (const float*)d_in[0];
    const float* Wq   = (const float*)d_in[1];
    const float* Wk   = (const float*)d_in[2];
    const float* Wv   = (const float*)d_in[3];
    const float* Wg   = (const float*)d_in[4];
    const float* bg   = (const float*)d_in[5];
    const float* Wo   = (const float*)d_in[6];
    const float* ln1w = (const float*)d_in[7];
    const float* ln1b = (const float*)d_in[8];
    const float* ln2w = (const float*)d_in[9];
    const float* ln2b = (const float*)d_in[10];
    const float* W1   = (const float*)d_in[11];
    const float* b1   = (const float*)d_in[12];
    const float* W2   = (const float*)d_in[13];
    const float* b2   = (const float*)d_in[14];
    float* out = (float*)d_out;

    char* ws = (char*)d_ws;
    u16*   wtQKVG = (u16*)(ws + 0);            // 4096x1024 bf16
    u16*   wtWo   = (u16*)(ws + 8388608);      // 1024x1024
    u16*   wtW1   = (u16*)(ws + 10485760);     // 4096x1024
    u16*   wtW2   = (u16*)(ws + 18874368);     // 1024x4096
    u16*   xnb    = (u16*)(ws + 27262976);     // 8192x1024 bf16
    u16*   qkvb   = (u16*)(ws + 44040192);     // 8192x3072 bf16
    float* gbuf   = (float*)(ws + 94371840);   // 8192x1024 f32
    u16*   kvT    = (u16*)(ws + 127926272);    // 32x64x64x64 bf16
    float* cdbuf  = (float*)(ws + 144703488);  // 32x64x64 f32
    u16*   qdecb  = (u16*)(ws + 145227776);    // 32x4096x64 bf16
    u16*   ointra = (u16*)(ws + 162004992);    // 32x4096x64 bf16
    u16*   STb    = (u16*)(ws + 178782208);    // 32x64x64x64 bf16
    u16*   obf    = (u16*)(ws + 195559424);    // 8192x1024 bf16
    u16*   hbf    = (u16*)(ws + 212336640);    // 8192x1024 bf16
    float* x2     = (float*)(ws + 94371840);   // over gbuf (dead after gla_a)
    u16*   ffnb   = (u16*)(ws + 27262976);     // over xnb+qkvb (dead after gla_a)

    if (ws_size < 229113856u) {
        fill_sentinel<<<dim3((out_size + 255) / 256), dim3(256), 0, stream>>>(out, out_size);
        return;
    }

    const dim3 b256(256), b512(512), b32x8(32, 8);

    transpose_bf16<<<dim3(32, 32),  b32x8, 0, stream>>>(Wq, wtQKVG,               1024, 1024);
    transpose_bf16<<<dim3(32, 32),  b32x8, 0, stream>>>(Wk, wtQKVG + 1024 * 1024, 1024, 1024);
    transpose_bf16<<<dim3(32, 32),  b32x8, 0, stream>>>(Wv, wtQKVG + 2048 * 1024, 1024, 1024);
    transpose_bf16<<<dim3(32, 32),  b32x8, 0, stream>>>(Wg, wtQKVG + 3072 * 1024, 1024, 1024);
    transpose_bf16<<<dim3(32, 32),  b32x8, 0, stream>>>(Wo, wtWo,                 1024, 1024);
    transpose_bf16<<<dim3(32, 128), b32x8, 0, stream>>>(W1, wtW1,                 1024, 4096);
    transpose_bf16<<<dim3(128, 32), b32x8, 0, stream>>>(W2, wtW2,                 4096, 1024);

    ln_bf16<<<dim3(8192), b256, 0, stream>>>(x, ln1w, ln1b, xnb);
    // fused q|k|v|gate GEMM: N=4096, epilogue splits bf16 qkv / f32 gate
    gemmL<0><<<dim3(64, 64), b256, 0, stream>>>(xnb, wtQKVG, gbuf, qkvb, nullptr, 8192, 4096, 1024);

    gla_a<<<dim3(2048), b256, 0, stream>>>(qkvb, gbuf, bg, qdecb, kvT, cdbuf, ointra);
    gla_scan<<<dim3(512), b256, 0, stream>>>(kvT, cdbuf, STb);
    gla_b<<<dim3(2048), b256, 0, stream>>>(qdecb, STb, ointra, obf);

    gemmM<2><<<dim3(32, 8), b512, 0, stream>>>(obf, wtWo, x2, nullptr, x, 8192, 1024, 1024);
    ln_bf16<<<dim3(8192), b256, 0, stream>>>(x2, ln2w, ln2b, hbf);
    gemmL<1><<<dim3(64, 64), b256, 0, stream>>>(hbf, wtW1, nullptr, ffnb, b1, 8192, 4096, 1024);
    gemmM<4><<<dim3(32, 8), b512, 0, stream>>>(ffnb, wtW2, out, b2, x2, 8192, 1024, 4096);
}

// Round 14
// 400.609 us; speedup vs baseline: 1.0382x; 1.0382x over previous
//
#include <hip/hip_runtime.h>

#define AS1 __attribute__((address_space(1)))
#define AS3 __attribute__((address_space(3)))

typedef unsigned short u16;
typedef short s16x8 __attribute__((ext_vector_type(8)));
typedef float f32x4 __attribute__((ext_vector_type(4)));

__device__ __forceinline__ float bf2f(u16 u) {
    union { unsigned u; float f; } v; v.u = ((unsigned)u) << 16; return v.f;
}
__device__ __forceinline__ u16 f2bf(float f) {
    union { float f; unsigned u; } v; v.f = f;
    unsigned u = v.u;
    return (u16)((u + 0x7FFFu + ((u >> 16) & 1u)) >> 16);
}

__device__ __forceinline__ void gload16(const void* g, void* l) {
    __builtin_amdgcn_global_load_lds((const AS1 void*)g, (AS3 void*)l, 16, 0, 0);
}

#define MFMA16(a, b, c) __builtin_amdgcn_mfma_f32_16x16x32_bf16(a, b, c, 0, 0, 0)

// ---------------------------------------------------------------- transpose+cvt
__global__ __launch_bounds__(256) void transpose_bf16(
    const float* __restrict__ src, u16* __restrict__ dst, int R, int C)
{
    __shared__ float t[32][33];
    const int tx = threadIdx.x, ty = threadIdx.y;
    const int r0 = blockIdx.x * 32, c0 = blockIdx.y * 32;
#pragma unroll
    for (int i = 0; i < 4; i++)
        t[ty + i * 8][tx] = src[(size_t)(r0 + ty + i * 8) * C + c0 + tx];
    __syncthreads();
#pragma unroll
    for (int i = 0; i < 4; i++)
        dst[(size_t)(c0 + ty + i * 8) * R + r0 + tx] = f2bf(t[tx][ty + i * 8]);
}

// ---------------------------------------------------------------- layernorm -> bf16
__global__ __launch_bounds__(256) void ln_bf16(
    const float* __restrict__ x, const float* __restrict__ w,
    const float* __restrict__ b, u16* __restrict__ out)
{
    __shared__ float red[8];
    const int row = blockIdx.x;
    const int tid = threadIdx.x;
    const size_t base = (size_t)row * 1024 + tid * 4;
    const float4 xv = *(const float4*)&x[base];
    float s = xv.x + xv.y + xv.z + xv.w;
    float q = xv.x * xv.x + xv.y * xv.y + xv.z * xv.z + xv.w * xv.w;
#pragma unroll
    for (int m = 1; m < 64; m <<= 1) { s += __shfl_xor(s, m); q += __shfl_xor(q, m); }
    if ((tid & 63) == 0) { red[tid >> 6] = s; red[4 + (tid >> 6)] = q; }
    __syncthreads();
    s = red[0] + red[1] + red[2] + red[3];
    q = red[4] + red[5] + red[6] + red[7];
    const float mu = s * (1.f / 1024.f);
    const float var = q * (1.f / 1024.f) - mu * mu;
    const float rs = rsqrtf(var + 1e-5f);
    const float4 wv = *(const float4*)&w[tid * 4];
    const float4 bv = *(const float4*)&b[tid * 4];
    uint2 ov;
    ov.x = (unsigned)f2bf((xv.x - mu) * rs * wv.x + bv.x) |
           ((unsigned)f2bf((xv.y - mu) * rs * wv.y + bv.y) << 16);
    ov.y = (unsigned)f2bf((xv.z - mu) * rs * wv.z + bv.z) |
           ((unsigned)f2bf((xv.w - mu) * rs * wv.w + bv.w) << 16);
    *(uint2*)&out[base] = ov;
}

// ---------------------------------------------------------------- 128x64 GEMM, 4 waves
// wave = 64x32 (4x2 frags, 32 AGPR acc). BK=64, single-buffer 24 KiB LDS.
// 6 blocks/CU (LDS 144/160 KiB, regs 72 <= 85): the confirmed occupancy lever.
// B^T input. EP: 0 = QKVG split; 1 = bf16 gelu(acc+bias); 2 = f32 +resid; 4 = f32 +bias+resid
template <int EPX>
__global__ __launch_bounds__(256, 6) void gemmL(
    const u16* __restrict__ A, const u16* __restrict__ BT,
    float* __restrict__ Cf, u16* __restrict__ Cb,
    const float* __restrict__ bias, const float* __restrict__ resid,
    int M, int N, int K)
{
    __shared__ u16 As[128 * 64];   // 16 KiB
    __shared__ u16 Bs[64 * 64];    // 8 KiB
    const int tid = threadIdx.x;
    const int w = tid >> 6, l = tid & 63;
    const int tm = blockIdx.x * 128, tn = blockIdx.y * 64;
    const int wr = w >> 1, wc = w & 1;    // wave: rows wr*64..+64, cols wc*32..+32

    // staging: LDS linear; source granule pre-swizzled (l&7)^(row&7), row&7 == (l>>3)&7
    const int srow = l >> 3;
    const int sg = ((l & 7) ^ (srow & 7)) * 8;
    int aSb[4], bSb[2];
#pragma unroll
    for (int j = 0; j < 4; j++)
        aSb[j] = (tm + w * 32 + j * 8 + srow) * K + sg;
#pragma unroll
    for (int j = 0; j < 2; j++)
        bSb[j] = (tn + w * 16 + j * 8 + srow) * K + sg;

    const int fr = l & 15, g0 = l >> 4, key = l & 7;
    const int arb = (wr * 64 + fr) * 64;
    const int brb = (wc * 32 + fr) * 64;

    f32x4 acc[4][2] = {};

#pragma unroll
    for (int j = 0; j < 4; j++) gload16(&A[aSb[j]], &As[(w * 32 + j * 8) * 64]);
#pragma unroll
    for (int j = 0; j < 2; j++) gload16(&BT[bSb[j]], &Bs[(w * 16 + j * 8) * 64]);

    const int NT = K >> 6;
    for (int t = 0; t < NT; ++t) {
        __syncthreads();
#pragma unroll
        for (int ks = 0; ks < 2; ks++) {
            const int g = ((ks * 4 + g0) ^ key) * 8;
            s16x8 b0 = *(const s16x8*)&Bs[brb + g];
            s16x8 b1 = *(const s16x8*)&Bs[brb + 16 * 64 + g];
            s16x8 a0 = *(const s16x8*)&As[arb + g];
            s16x8 a1 = *(const s16x8*)&As[arb + 16 * 64 + g];
            s16x8 a2 = *(const s16x8*)&As[arb + 32 * 64 + g];
            s16x8 a3 = *(const s16x8*)&As[arb + 48 * 64 + g];
            acc[0][0] = MFMA16(a0, b0, acc[0][0]);
            acc[0][1] = MFMA16(a0, b1, acc[0][1]);
            acc[1][0] = MFMA16(a1, b0, acc[1][0]);
            acc[1][1] = MFMA16(a1, b1, acc[1][1]);
            acc[2][0] = MFMA16(a2, b0, acc[2][0]);
            acc[2][1] = MFMA16(a2, b1, acc[2][1]);
            acc[3][0] = MFMA16(a3, b0, acc[3][0]);
            acc[3][1] = MFMA16(a3, b1, acc[3][1]);
        }
        if (t + 1 < NT) {
            __syncthreads();
            const int k0 = (t + 1) * 64;
#pragma unroll
            for (int j = 0; j < 4; j++) gload16(&A[aSb[j] + k0], &As[(w * 32 + j * 8) * 64]);
#pragma unroll
            for (int j = 0; j < 2; j++) gload16(&BT[bSb[j] + k0], &Bs[(w * 16 + j * 8) * 64]);
        }
    }

    // epilogue. C/D 16x16: col = l&15, row = (l>>4)*4 + r
    const int erow0 = tm + wr * 64 + (l >> 4) * 4;
    const int ecol0 = tn + wc * 32 + (l & 15);
#pragma unroll
    for (int i = 0; i < 4; i++) {
#pragma unroll
        for (int j = 0; j < 2; j++) {
            const int col = ecol0 + j * 16;
#pragma unroll
            for (int r = 0; r < 4; r++) {
                const int row = erow0 + i * 16 + r;
                const float v = acc[i][j][r];
                if (EPX == 0) {
                    if (col < 3072) Cb[(size_t)row * 3072 + col] = f2bf(v);
                    else            Cf[(size_t)row * 1024 + (col - 3072)] = v;
                } else if (EPX == 1) {
                    const float u2 = v + bias[col];
                    Cb[(size_t)row * N + col] =
                        f2bf(0.5f * u2 * (1.f + erff(u2 * 0.70710678118654752f)));
                } else if (EPX == 2) {
                    const size_t idx = (size_t)row * N + col;
                    Cf[idx] = v + resid[idx];
                } else {
                    const size_t idx = (size_t)row * N + col;
                    Cf[idx] = v + bias[col] + resid[idx];
                }
            }
        }
    }
}

// ---------------------------------------------------------------- GLA phase A (MFMA)
#define TP 72
#define LP 65
__global__ __launch_bounds__(256) void gla_a(
    const u16* __restrict__ qkv,
    const float* __restrict__ g,
    const float* __restrict__ bg,
    u16* __restrict__ qdec,
    u16* __restrict__ kvT,
    float* __restrict__ cdec,
    u16* __restrict__ ointra)
{
    __shared__ u16 Qh[64 * TP];
    __shared__ u16 Kh[64 * TP];
    __shared__ u16 VT[64 * TP];
    __shared__ float L[64 * LP];
    __shared__ float lm[64], nq[64], nk[64];

    const int bid = blockIdx.x;
    const int bh = bid >> 6, ck = bid & 63;
    const int b = bh >> 4, h = bh & 15;
    const int tok0 = b * 4096 + ck * 64;
    const int tid = threadIdx.x;
    const int w = tid >> 6, l = tid & 63;

#pragma unroll
    for (int pass = 0; pass < 2; pass++) {
        const int c = (tid >> 3) + pass * 32;
        const int col = (tid & 7) * 8;
        const size_t rb = (size_t)(tok0 + c) * 3072 + h * 64 + col;
        uint4 qv = *(const uint4*)&qkv[rb];
        uint4 kv_ = *(const uint4*)&qkv[rb + 1024];
        uint4 vv = *(const uint4*)&qkv[rb + 2048];
        *(uint4*)&Qh[c * TP + col] = qv;
        *(uint4*)&Kh[c * TP + col] = kv_;
        const u16* va = (const u16*)&vv;
#pragma unroll
        for (int j = 0; j < 8; j++) VT[(col + j) * TP + c] = va[j];
    }
#pragma unroll
    for (int pass = 0; pass < 4; pass++) {
        const int c = (tid >> 4) + pass * 16;
        const int col = (tid & 15) * 4;
        float4 gv = *(const float4*)&g[(size_t)(tok0 + c) * 1024 + h * 64 + col];
        float4 bgv = *(const float4*)&bg[h * 64 + col];
        const float* ga = (const float*)&gv;
        const float* ba = (const float*)&bgv;
#pragma unroll
        for (int i = 0; i < 4; i++) {
            const float z = ga[i] + ba[i];
            const float al = 1.f / (1.f + __expf(-z));
            L[c * LP + col + i] = __logf(fmaxf(al, 1e-6f));
        }
    }
    __syncthreads();

    {
        const int d = tid >> 2, qq = tid & 3;
        float vals[16];
#pragma unroll
        for (int i = 0; i < 16; i++) vals[i] = L[(qq * 16 + i) * LP + d];
        float s = 0.f;
#pragma unroll
        for (int i = 0; i < 16; i++) { s += vals[i]; vals[i] = s; }
        float sum = s;
        float u1 = __shfl_up(sum, 1, 4); if (qq >= 1) sum += u1;
        float u2 = __shfl_up(sum, 2, 4); if (qq >= 2) sum += u2;
        const float excl = sum - s;
#pragma unroll
        for (int i = 0; i < 16; i++) L[(qq * 16 + i) * LP + d] = vals[i] + excl;
        if (qq == 3) cdec[((size_t)bh * 64 + ck) * 64 + d] = __expf(sum);
    }
    __syncthreads();

    {
        const int c = tid >> 2, qq = tid & 3;
        float sl = 0.f, sq = 0.f, sk = 0.f;
        uint4 qa = *(const uint4*)&Qh[c * TP + qq * 16];
        uint4 qb = *(const uint4*)&Qh[c * TP + qq * 16 + 8];
        uint4 ka = *(const uint4*)&Kh[c * TP + qq * 16];
        uint4 kb = *(const uint4*)&Kh[c * TP + qq * 16 + 8];
        const u16* qu = (const u16*)&qa; const u16* qu2 = (const u16*)&qb;
        const u16* ku = (const u16*)&ka; const u16* ku2 = (const u16*)&kb;
#pragma unroll
        for (int i = 0; i < 8; i++) {
            float q1 = bf2f(qu[i]), q2 = bf2f(qu2[i]);
            float k1 = bf2f(ku[i]), k2 = bf2f(ku2[i]);
            sq += q1 * q1 + q2 * q2;
            sk += k1 * k1 + k2 * k2;
        }
#pragma unroll
        for (int i = 0; i < 16; i++) sl += L[c * LP + qq * 16 + i];
        sl += __shfl_xor(sl, 1); sl += __shfl_xor(sl, 2);
        sq += __shfl_xor(sq, 1); sq += __shfl_xor(sq, 2);
        sk += __shfl_xor(sk, 1); sk += __shfl_xor(sk, 2);
        if (qq == 0) {
            lm[c] = sl * (1.f / 64.f);
            nq[c] = 1.f / fmaxf(sqrtf(sq), 1e-12f);
            nk[c] = 1.f / fmaxf(sqrtf(sk), 1e-12f);
        }
    }
    __syncthreads();

    u16 kdt[16];
    {
        const int c = tid >> 2, qq = tid & 3;
        const float qn = nq[c], kn = nk[c];
        uint4 qa = *(const uint4*)&Qh[c * TP + qq * 16];
        uint4 qb = *(const uint4*)&Qh[c * TP + qq * 16 + 8];
        uint4 ka = *(const uint4*)&Kh[c * TP + qq * 16];
        uint4 kb = *(const uint4*)&Kh[c * TP + qq * 16 + 8];
        u16* qu = (u16*)&qa; u16* qu2 = (u16*)&qb;
        u16* ku = (u16*)&ka; u16* ku2 = (u16*)&kb;
        float Lc[16], Le[16];
#pragma unroll
        for (int i = 0; i < 16; i++) {
            Lc[i] = L[c * LP + qq * 16 + i];
            Le[i] = L[63 * LP + qq * 16 + i];
        }
        unsigned pk[8];
#pragma unroll
        for (int i = 0; i < 8; i++) {
            float qh1 = bf2f(qu[i]) * qn;  qu[i] = f2bf(qh1);
            float qh2 = bf2f(qu2[i]) * qn; qu2[i] = f2bf(qh2);
            float kh1 = bf2f(ku[i]) * kn;  ku[i] = f2bf(kh1);
            float kh2 = bf2f(ku2[i]) * kn; ku2[i] = f2bf(kh2);
            kdt[i]     = f2bf(kh1 * __expf(Le[i] - Lc[i]));
            kdt[i + 8] = f2bf(kh2 * __expf(Le[i + 8] - Lc[i + 8]));
        }
#pragma unroll
        for (int i = 0; i < 4; i++) {
            pk[i] = (unsigned)f2bf(bf2f(qu[2 * i]) * __expf(Lc[2 * i])) |
                    ((unsigned)f2bf(bf2f(qu[2 * i + 1]) * __expf(Lc[2 * i + 1])) << 16);
            pk[4 + i] = (unsigned)f2bf(bf2f(qu2[2 * i]) * __expf(Lc[8 + 2 * i])) |
                        ((unsigned)f2bf(bf2f(qu2[2 * i + 1]) * __expf(Lc[8 + 2 * i + 1])) << 16);
        }
        *(uint4*)&Qh[c * TP + qq * 16] = qa;
        *(uint4*)&Qh[c * TP + qq * 16 + 8] = qb;
        *(uint4*)&Kh[c * TP + qq * 16] = ka;
        *(uint4*)&Kh[c * TP + qq * 16 + 8] = kb;
        u16* qrow = &qdec[((size_t)bh * 4096 + ck * 64 + c) * 64 + qq * 16];
        *(uint4*)&qrow[0] = *(const uint4*)&pk[0];
        *(uint4*)&qrow[8] = *(const uint4*)&pk[4];
    }
    __syncthreads();

    u16* KDT = (u16*)L;
    {
        const int c = tid >> 2, qq = tid & 3;
#pragma unroll
        for (int i = 0; i < 16; i++) KDT[(qq * 16 + i) * TP + c] = kdt[i];
    }
    const int fr = l & 15;
    const int kk = (l >> 4) * 8;
    f32x4 accS[4] = {};
#pragma unroll
    for (int ks = 0; ks < 2; ks++) {
        s16x8 af = *(const s16x8*)&Qh[(w * 16 + fr) * TP + ks * 32 + kk];
#pragma unroll
        for (int j = 0; j < 4; j++) {
            s16x8 bf = *(const s16x8*)&Kh[(j * 16 + fr) * TP + ks * 32 + kk];
            accS[j] = MFMA16(af, bf, accS[j]);
        }
    }
    __syncthreads();

    {
        const int erow = w * 16 + (l >> 4) * 4;
#pragma unroll
        for (int j = 0; j < 4; j++) {
            const int mm = j * 16 + (l & 15);
            const float lmm = lm[mm];
#pragma unroll
            for (int r = 0; r < 4; r++) {
                const int cc = erow + r;
                const float wgt = (mm <= cc) ? __expf(lm[cc] - lmm) : 0.f;
                Qh[cc * TP + mm] = f2bf(accS[j][r] * wgt);
            }
        }
    }
    __syncthreads();

    f32x4 accO[4] = {};
    f32x4 accK[4] = {};
#pragma unroll
    for (int ks = 0; ks < 2; ks++) {
        s16x8 aAt = *(const s16x8*)&Qh[(w * 16 + fr) * TP + ks * 32 + kk];
        s16x8 aVt = *(const s16x8*)&VT[(w * 16 + fr) * TP + ks * 32 + kk];
#pragma unroll
        for (int j = 0; j < 4; j++) {
            s16x8 bVt = *(const s16x8*)&VT[(j * 16 + fr) * TP + ks * 32 + kk];
            s16x8 bKd = *(const s16x8*)&KDT[(j * 16 + fr) * TP + ks * 32 + kk];
            accO[j] = MFMA16(aAt, bVt, accO[j]);
            accK[j] = MFMA16(aVt, bKd, accK[j]);
        }
    }
    {
        const int erow = w * 16 + (l >> 4) * 4;
#pragma unroll
        for (int j = 0; j < 4; j++) {
            const int col = j * 16 + (l & 15);
#pragma unroll
            for (int r = 0; r < 4; r++) {
                const int row = erow + r;
                ointra[((size_t)bh * 4096 + ck * 64 + row) * 64 + col] = f2bf(accO[j][r]);
                kvT[(((size_t)bh * 64 + ck) * 64 + row) * 64 + col] = f2bf(accK[j][r]);
            }
        }
    }
}

// ---------------------------------------------------------------- elementwise chunk scan
__global__ __launch_bounds__(256) void gla_scan(
    const u16* __restrict__ kvT, const float* __restrict__ cdec,
    u16* __restrict__ ST)
{
    const int bh = blockIdx.x >> 4;
    const int de = (blockIdx.x & 15) * 256 + threadIdx.x;
    const int d = de & 63;
    float s = 0.f;
    const size_t base = (size_t)bh * 64 * 4096 + de;
    const size_t cb = (size_t)bh * 4096 + d;
    for (int t = 0; t < 64; t++) {
        ST[base + (size_t)t * 4096] = f2bf(s);
        s = s * cdec[cb + (size_t)t * 64] + bf2f(kvT[base + (size_t)t * 4096]);
    }
}

// ---------------------------------------------------------------- GLA phase B (MFMA)
__global__ __launch_bounds__(256) void gla_b(
    const u16* __restrict__ qdec, const u16* __restrict__ ST,
    const u16* __restrict__ ointra, u16* __restrict__ obf)
{
    __shared__ u16 Qd[64 * TP];
    __shared__ u16 Sd[64 * TP];
    const int bid = blockIdx.x;
    const int bh = bid >> 6, ck = bid & 63;
    const int b = bh >> 4, h = bh & 15;
    const int tid = threadIdx.x;
    const int w = tid >> 6, l = tid & 63;
#pragma unroll
    for (int pass = 0; pass < 2; pass++) {
        const int r = (tid >> 3) + pass * 32;
        const int col = (tid & 7) * 8;
        *(uint4*)&Qd[r * TP + col] =
            *(const uint4*)&qdec[((size_t)bh * 4096 + ck * 64 + r) * 64 + col];
        *(uint4*)&Sd[r * TP + col] =
            *(const uint4*)&ST[(((size_t)bh * 64 + ck) * 64 + r) * 64 + col];
    }
    __syncthreads();
    const int fr = l & 15;
    const int kk = (l >> 4) * 8;
    f32x4 acc[4] = {};
#pragma unroll
    for (int ks = 0; ks < 2; ks++) {
        s16x8 af = *(const s16x8*)&Qd[(w * 16 + fr) * TP + ks * 32 + kk];
#pragma unroll
        for (int j = 0; j < 4; j++) {
            s16x8 bf = *(const s16x8*)&Sd[(j * 16 + fr) * TP + ks * 32 + kk];
            acc[j] = MFMA16(af, bf, acc[j]);
        }
    }
    const int erow = w * 16 + (l >> 4) * 4;
#pragma unroll
    for (int j = 0; j < 4; j++) {
        const int e = j * 16 + (l & 15);
#pragma unroll
        for (int r = 0; r < 4; r++) {
            const int cc = erow + r;
            const size_t ia = ((size_t)bh * 4096 + ck * 64 + cc) * 64 + e;
            const float v = acc[j][r] + bf2f(ointra[ia]);
            obf[(size_t)(b * 4096 + ck * 64 + cc) * 1024 + h * 64 + e] = f2bf(v);
        }
    }
}

__global__ void fill_sentinel(float* out, int n) {
    int i = blockIdx.x * 256 + threadIdx.x;
    if (i < n) out[i] = 12345.0f;
}

// ---------------------------------------------------------------- host launcher
extern "C" void kernel_launch(void* const* d_in, const int* in_sizes, int n_in,
                              void* d_out, int out_size, void* d_ws, size_t ws_size,
                              hipStream_t stream)
{
    const float* x    = (const float*)d_in[0];
    const float* Wq   = (const float*)d_in[1];
    const float* Wk   = (const float*)d_in[2];
    const float* Wv   = (const float*)d_in[3];
    const float* Wg   = (const float*)d_in[4];
    const float* bg   = (const float*)d_in[5];
    const float* Wo   = (const float*)d_in[6];
    const float* ln1w = (const float*)d_in[7];
    const float* ln1b = (const float*)d_in[8];
    const float* ln2w = (const float*)d_in[9];
    const float* ln2b = (const float*)d_in[10];
    const float* W1   = (const float*)d_in[11];
    const float* b1   = (const float*)d_in[12];
    const float* W2   = (const float*)d_in[13];
    const float* b2   = (const float*)d_in[14];
    float* out = (float*)d_out;

    char* ws = (char*)d_ws;
    u16*   wtQKVG = (u16*)(ws + 0);            // 4096x1024 bf16
    u16*   wtWo   = (u16*)(ws + 8388608);      // 1024x1024
    u16*   wtW1   = (u16*)(ws + 10485760);     // 4096x1024
    u16*   wtW2   = (u16*)(ws + 18874368);     // 1024x4096
    u16*   xnb    = (u16*)(ws + 27262976);     // 8192x1024 bf16
    u16*   qkvb   = (u16*)(ws + 44040192);     // 8192x3072 bf16
    float* gbuf   = (float*)(ws + 94371840);   // 8192x1024 f32
    u16*   kvT    = (u16*)(ws + 127926272);    // 32x64x64x64 bf16
    float* cdbuf  = (float*)(ws + 144703488);  // 32x64x64 f32
    u16*   qdecb  = (u16*)(ws + 145227776);    // 32x4096x64 bf16
    u16*   ointra = (u16*)(ws + 162004992);    // 32x4096x64 bf16
    u16*   STb    = (u16*)(ws + 178782208);    // 32x64x64x64 bf16
    u16*   obf    = (u16*)(ws + 195559424);    // 8192x1024 bf16
    u16*   hbf    = (u16*)(ws + 212336640);    // 8192x1024 bf16
    float* x2     = (float*)(ws + 94371840);   // over gbuf (dead after gla_a)
    u16*   ffnb   = (u16*)(ws + 27262976);     // over xnb+qkvb (dead after gla_a)

    if (ws_size < 229113856u) {
        fill_sentinel<<<dim3((out_size + 255) / 256), dim3(256), 0, stream>>>(out, out_size);
        return;
    }

    const dim3 b256(256), b32x8(32, 8);

    transpose_bf16<<<dim3(32, 32),  b32x8, 0, stream>>>(Wq, wtQKVG,               1024, 1024);
    transpose_bf16<<<dim3(32, 32),  b32x8, 0, stream>>>(Wk, wtQKVG + 1024 * 1024, 1024, 1024);
    transpose_bf16<<<dim3(32, 32),  b32x8, 0, stream>>>(Wv, wtQKVG + 2048 * 1024, 1024, 1024);
    transpose_bf16<<<dim3(32, 32),  b32x8, 0, stream>>>(Wg, wtQKVG + 3072 * 1024, 1024, 1024);
    transpose_bf16<<<dim3(32, 32),  b32x8, 0, stream>>>(Wo, wtWo,                 1024, 1024);
    transpose_bf16<<<dim3(32, 128), b32x8, 0, stream>>>(W1, wtW1,                 1024, 4096);
    transpose_bf16<<<dim3(128, 32), b32x8, 0, stream>>>(W2, wtW2,                 4096, 1024);

    ln_bf16<<<dim3(8192), b256, 0, stream>>>(x, ln1w, ln1b, xnb);
    // fused q|k|v|gate GEMM: N=4096, epilogue splits bf16 qkv / f32 gate
    gemmL<0><<<dim3(64, 64), b256, 0, stream>>>(xnb, wtQKVG, gbuf, qkvb, nullptr, nullptr, 8192, 4096, 1024);

    gla_a<<<dim3(2048), b256, 0, stream>>>(qkvb, gbuf, bg, qdecb, kvT, cdbuf, ointra);
    gla_scan<<<dim3(512), b256, 0, stream>>>(kvT, cdbuf, STb);
    gla_b<<<dim3(2048), b256, 0, stream>>>(qdecb, STb, ointra, obf);

    gemmL<2><<<dim3(64, 16), b256, 0, stream>>>(obf, wtWo, x2, nullptr, nullptr, x, 8192, 1024, 1024);
    ln_bf16<<<dim3(8192), b256, 0, stream>>>(x2, ln2w, ln2b, hbf);
    gemmL<1><<<dim3(64, 64), b256, 0, stream>>>(hbf, wtW1, nullptr, ffnb, b1, nullptr, 8192, 4096, 1024);
    gemmL<4><<<dim3(64, 16), b256, 0, stream>>>(ffnb, wtW2, out, nullptr, b2, x2, 8192, 1024, 4096);
}

// Round 15
// 386.785 us; speedup vs baseline: 1.0753x; 1.0357x over previous
//
#include <hip/hip_runtime.h>

#define AS1 __attribute__((address_space(1)))
#define AS3 __attribute__((address_space(3)))

typedef unsigned short u16;
typedef short s16x8 __attribute__((ext_vector_type(8)));
typedef float f32x4 __attribute__((ext_vector_type(4)));

__device__ __forceinline__ float bf2f(u16 u) {
    union { unsigned u; float f; } v; v.u = ((unsigned)u) << 16; return v.f;
}
__device__ __forceinline__ u16 f2bf(float f) {
    union { float f; unsigned u; } v; v.f = f;
    unsigned u = v.u;
    return (u16)((u + 0x7FFFu + ((u >> 16) & 1u)) >> 16);
}

__device__ __forceinline__ void gload16(const void* g, void* l) {
    __builtin_amdgcn_global_load_lds((const AS1 void*)g, (AS3 void*)l, 16, 0, 0);
}

#define MFMA16(a, b, c) __builtin_amdgcn_mfma_f32_16x16x32_bf16(a, b, c, 0, 0, 0)

// ---------------------------------------------------------------- batched weight transpose+cvt
// One launch for all 7 weight matrices. Block = (32,8), 32x32 tile each.
__global__ __launch_bounds__(256) void transpose_all(
    const float* __restrict__ Wq, const float* __restrict__ Wk,
    const float* __restrict__ Wv, const float* __restrict__ Wg,
    const float* __restrict__ Wo, const float* __restrict__ W1,
    const float* __restrict__ W2,
    u16* __restrict__ wtQKVG, u16* __restrict__ wtWo,
    u16* __restrict__ wtW1, u16* __restrict__ wtW2)
{
    __shared__ float t[32][33];
    const int bid = blockIdx.x;
    const float* src; u16* dst; int R, C, loc;
    if (bid < 4096) {               // Wq|Wk|Wv|Wg: 1024x1024 each
        const int j = bid >> 10; loc = bid & 1023;
        src = (j == 0) ? Wq : (j == 1) ? Wk : (j == 2) ? Wv : Wg;
        dst = wtQKVG + (size_t)j * 1024 * 1024; R = 1024; C = 1024;
    } else if (bid < 5120) {        // Wo: 1024x1024
        loc = bid - 4096; src = Wo; dst = wtWo; R = 1024; C = 1024;
    } else if (bid < 9216) {        // W1: 1024x4096
        loc = bid - 5120; src = W1; dst = wtW1; R = 1024; C = 4096;
    } else {                        // W2: 4096x1024
        loc = bid - 9216; src = W2; dst = wtW2; R = 4096; C = 1024;
    }
    const int tx_ = R >> 5;
    const int r0 = (loc % tx_) * 32, c0 = (loc / tx_) * 32;
    const int tx = threadIdx.x, ty = threadIdx.y;
#pragma unroll
    for (int i = 0; i < 4; i++)
        t[ty + i * 8][tx] = src[(size_t)(r0 + ty + i * 8) * C + c0 + tx];
    __syncthreads();
#pragma unroll
    for (int i = 0; i < 4; i++)
        dst[(size_t)(c0 + ty + i * 8) * R + r0 + tx] = f2bf(t[tx][ty + i * 8]);
}

// ---------------------------------------------------------------- layernorm -> bf16
__global__ __launch_bounds__(256) void ln_bf16(
    const float* __restrict__ x, const float* __restrict__ w,
    const float* __restrict__ b, u16* __restrict__ out)
{
    __shared__ float red[8];
    const int row = blockIdx.x;
    const int tid = threadIdx.x;
    const size_t base = (size_t)row * 1024 + tid * 4;
    const float4 xv = *(const float4*)&x[base];
    float s = xv.x + xv.y + xv.z + xv.w;
    float q = xv.x * xv.x + xv.y * xv.y + xv.z * xv.z + xv.w * xv.w;
#pragma unroll
    for (int m = 1; m < 64; m <<= 1) { s += __shfl_xor(s, m); q += __shfl_xor(q, m); }
    if ((tid & 63) == 0) { red[tid >> 6] = s; red[4 + (tid >> 6)] = q; }
    __syncthreads();
    s = red[0] + red[1] + red[2] + red[3];
    q = red[4] + red[5] + red[6] + red[7];
    const float mu = s * (1.f / 1024.f);
    const float var = q * (1.f / 1024.f) - mu * mu;
    const float rs = rsqrtf(var + 1e-5f);
    const float4 wv = *(const float4*)&w[tid * 4];
    const float4 bv = *(const float4*)&b[tid * 4];
    uint2 ov;
    ov.x = (unsigned)f2bf((xv.x - mu) * rs * wv.x + bv.x) |
           ((unsigned)f2bf((xv.y - mu) * rs * wv.y + bv.y) << 16);
    ov.y = (unsigned)f2bf((xv.z - mu) * rs * wv.z + bv.z) |
           ((unsigned)f2bf((xv.w - mu) * rs * wv.w + bv.w) << 16);
    *(uint2*)&out[base] = ov;
}

// ---------------------------------------------------------------- 128x64 GEMM, 4 waves
// wave = 64x32 (4x2 frags, 32 AGPR acc). BK=64, single-buffer 24 KiB LDS.
// B^T input. EP: 0 = QKVG split; 1 = bf16 gelu(acc+bias); 2 = f32 +resid; 4 = f32 +bias+resid
template <int EPX>
__global__ __launch_bounds__(256, 6) void gemmL(
    const u16* __restrict__ A, const u16* __restrict__ BT,
    float* __restrict__ Cf, u16* __restrict__ Cb,
    const float* __restrict__ bias, const float* __restrict__ resid,
    int M, int N, int K)
{
    __shared__ u16 As[128 * 64];   // 16 KiB
    __shared__ u16 Bs[64 * 64];    // 8 KiB
    const int tid = threadIdx.x;
    const int w = tid >> 6, l = tid & 63;
    const int tm = blockIdx.x * 128, tn = blockIdx.y * 64;
    const int wr = w >> 1, wc = w & 1;

    const int srow = l >> 3;
    const int sg = ((l & 7) ^ (srow & 7)) * 8;
    int aSb[4], bSb[2];
#pragma unroll
    for (int j = 0; j < 4; j++)
        aSb[j] = (tm + w * 32 + j * 8 + srow) * K + sg;
#pragma unroll
    for (int j = 0; j < 2; j++)
        bSb[j] = (tn + w * 16 + j * 8 + srow) * K + sg;

    const int fr = l & 15, g0 = l >> 4, key = l & 7;
    const int arb = (wr * 64 + fr) * 64;
    const int brb = (wc * 32 + fr) * 64;

    f32x4 acc[4][2] = {};

#pragma unroll
    for (int j = 0; j < 4; j++) gload16(&A[aSb[j]], &As[(w * 32 + j * 8) * 64]);
#pragma unroll
    for (int j = 0; j < 2; j++) gload16(&BT[bSb[j]], &Bs[(w * 16 + j * 8) * 64]);

    const int NT = K >> 6;
    for (int t = 0; t < NT; ++t) {
        __syncthreads();
#pragma unroll
        for (int ks = 0; ks < 2; ks++) {
            const int g = ((ks * 4 + g0) ^ key) * 8;
            s16x8 b0 = *(const s16x8*)&Bs[brb + g];
            s16x8 b1 = *(const s16x8*)&Bs[brb + 16 * 64 + g];
            s16x8 a0 = *(const s16x8*)&As[arb + g];
            s16x8 a1 = *(const s16x8*)&As[arb + 16 * 64 + g];
            s16x8 a2 = *(const s16x8*)&As[arb + 32 * 64 + g];
            s16x8 a3 = *(const s16x8*)&As[arb + 48 * 64 + g];
            acc[0][0] = MFMA16(a0, b0, acc[0][0]);
            acc[0][1] = MFMA16(a0, b1, acc[0][1]);
            acc[1][0] = MFMA16(a1, b0, acc[1][0]);
            acc[1][1] = MFMA16(a1, b1, acc[1][1]);
            acc[2][0] = MFMA16(a2, b0, acc[2][0]);
            acc[2][1] = MFMA16(a2, b1, acc[2][1]);
            acc[3][0] = MFMA16(a3, b0, acc[3][0]);
            acc[3][1] = MFMA16(a3, b1, acc[3][1]);
        }
        if (t + 1 < NT) {
            __syncthreads();
            const int k0 = (t + 1) * 64;
#pragma unroll
            for (int j = 0; j < 4; j++) gload16(&A[aSb[j] + k0], &As[(w * 32 + j * 8) * 64]);
#pragma unroll
            for (int j = 0; j < 2; j++) gload16(&BT[bSb[j] + k0], &Bs[(w * 16 + j * 8) * 64]);
        }
    }

    const int erow0 = tm + wr * 64 + (l >> 4) * 4;
    const int ecol0 = tn + wc * 32 + (l & 15);
#pragma unroll
    for (int i = 0; i < 4; i++) {
#pragma unroll
        for (int j = 0; j < 2; j++) {
            const int col = ecol0 + j * 16;
#pragma unroll
            for (int r = 0; r < 4; r++) {
                const int row = erow0 + i * 16 + r;
                const float v = acc[i][j][r];
                if (EPX == 0) {
                    if (col < 3072) Cb[(size_t)row * 3072 + col] = f2bf(v);
                    else            Cf[(size_t)row * 1024 + (col - 3072)] = v;
                } else if (EPX == 1) {
                    const float u2 = v + bias[col];
                    Cb[(size_t)row * N + col] =
                        f2bf(0.5f * u2 * (1.f + erff(u2 * 0.70710678118654752f)));
                } else if (EPX == 2) {
                    const size_t idx = (size_t)row * N + col;
                    Cf[idx] = v + resid[idx];
                } else {
                    const size_t idx = (size_t)row * N + col;
                    Cf[idx] = v + bias[col] + resid[idx];
                }
            }
        }
    }
}

// ---------------------------------------------------------------- GLA phase A (MFMA)
#define TP 72
#define LP 65
__global__ __launch_bounds__(256) void gla_a(
    const u16* __restrict__ qkv,
    const float* __restrict__ g,
    const float* __restrict__ bg,
    u16* __restrict__ qdec,
    u16* __restrict__ kvT,
    float* __restrict__ cdec,
    u16* __restrict__ ointra)
{
    __shared__ u16 Qh[64 * TP];
    __shared__ u16 Kh[64 * TP];
    __shared__ u16 VT[64 * TP];
    __shared__ float L[64 * LP];
    __shared__ float lm[64], nq[64], nk[64];

    const int bid = blockIdx.x;
    const int bh = bid >> 6, ck = bid & 63;
    const int b = bh >> 4, h = bh & 15;
    const int tok0 = b * 4096 + ck * 64;
    const int tid = threadIdx.x;
    const int w = tid >> 6, l = tid & 63;

#pragma unroll
    for (int pass = 0; pass < 2; pass++) {
        const int c = (tid >> 3) + pass * 32;
        const int col = (tid & 7) * 8;
        const size_t rb = (size_t)(tok0 + c) * 3072 + h * 64 + col;
        uint4 qv = *(const uint4*)&qkv[rb];
        uint4 kv_ = *(const uint4*)&qkv[rb + 1024];
        uint4 vv = *(const uint4*)&qkv[rb + 2048];
        *(uint4*)&Qh[c * TP + col] = qv;
        *(uint4*)&Kh[c * TP + col] = kv_;
        const u16* va = (const u16*)&vv;
#pragma unroll
        for (int j = 0; j < 8; j++) VT[(col + j) * TP + c] = va[j];
    }
#pragma unroll
    for (int pass = 0; pass < 4; pass++) {
        const int c = (tid >> 4) + pass * 16;
        const int col = (tid & 15) * 4;
        float4 gv = *(const float4*)&g[(size_t)(tok0 + c) * 1024 + h * 64 + col];
        float4 bgv = *(const float4*)&bg[h * 64 + col];
        const float* ga = (const float*)&gv;
        const float* ba = (const float*)&bgv;
#pragma unroll
        for (int i = 0; i < 4; i++) {
            const float z = ga[i] + ba[i];
            const float al = 1.f / (1.f + __expf(-z));
            L[c * LP + col + i] = __logf(fmaxf(al, 1e-6f));
        }
    }
    __syncthreads();

    {
        const int d = tid >> 2, qq = tid & 3;
        float vals[16];
#pragma unroll
        for (int i = 0; i < 16; i++) vals[i] = L[(qq * 16 + i) * LP + d];
        float s = 0.f;
#pragma unroll
        for (int i = 0; i < 16; i++) { s += vals[i]; vals[i] = s; }
        float sum = s;
        float u1 = __shfl_up(sum, 1, 4); if (qq >= 1) sum += u1;
        float u2 = __shfl_up(sum, 2, 4); if (qq >= 2) sum += u2;
        const float excl = sum - s;
#pragma unroll
        for (int i = 0; i < 16; i++) L[(qq * 16 + i) * LP + d] = vals[i] + excl;
        if (qq == 3) cdec[((size_t)bh * 64 + ck) * 64 + d] = __expf(sum);
    }
    __syncthreads();

    {
        const int c = tid >> 2, qq = tid & 3;
        float sl = 0.f, sq = 0.f, sk = 0.f;
        uint4 qa = *(const uint4*)&Qh[c * TP + qq * 16];
        uint4 qb = *(const uint4*)&Qh[c * TP + qq * 16 + 8];
        uint4 ka = *(const uint4*)&Kh[c * TP + qq * 16];
        uint4 kb = *(const uint4*)&Kh[c * TP + qq * 16 + 8];
        const u16* qu = (const u16*)&qa; const u16* qu2 = (const u16*)&qb;
        const u16* ku = (const u16*)&ka; const u16* ku2 = (const u16*)&kb;
#pragma unroll
        for (int i = 0; i < 8; i++) {
            float q1 = bf2f(qu[i]), q2 = bf2f(qu2[i]);
            float k1 = bf2f(ku[i]), k2 = bf2f(ku2[i]);
            sq += q1 * q1 + q2 * q2;
            sk += k1 * k1 + k2 * k2;
        }
#pragma unroll
        for (int i = 0; i < 16; i++) sl += L[c * LP + qq * 16 + i];
        sl += __shfl_xor(sl, 1); sl += __shfl_xor(sl, 2);
        sq += __shfl_xor(sq, 1); sq += __shfl_xor(sq, 2);
        sk += __shfl_xor(sk, 1); sk += __shfl_xor(sk, 2);
        if (qq == 0) {
            lm[c] = sl * (1.f / 64.f);
            nq[c] = 1.f / fmaxf(sqrtf(sq), 1e-12f);
            nk[c] = 1.f / fmaxf(sqrtf(sk), 1e-12f);
        }
    }
    __syncthreads();

    u16 kdt[16];
    {
        const int c = tid >> 2, qq = tid & 3;
        const float qn = nq[c], kn = nk[c];
        uint4 qa = *(const uint4*)&Qh[c * TP + qq * 16];
        uint4 qb = *(const uint4*)&Qh[c * TP + qq * 16 + 8];
        uint4 ka = *(const uint4*)&Kh[c * TP + qq * 16];
        uint4 kb = *(const uint4*)&Kh[c * TP + qq * 16 + 8];
        u16* qu = (u16*)&qa; u16* qu2 = (u16*)&qb;
        u16* ku = (u16*)&ka; u16* ku2 = (u16*)&kb;
        float Lc[16], Le[16];
#pragma unroll
        for (int i = 0; i < 16; i++) {
            Lc[i] = L[c * LP + qq * 16 + i];
            Le[i] = L[63 * LP + qq * 16 + i];
        }
        unsigned pk[8];
#pragma unroll
        for (int i = 0; i < 8; i++) {
            float qh1 = bf2f(qu[i]) * qn;  qu[i] = f2bf(qh1);
            float qh2 = bf2f(qu2[i]) * qn; qu2[i] = f2bf(qh2);
            float kh1 = bf2f(ku[i]) * kn;  ku[i] = f2bf(kh1);
            float kh2 = bf2f(ku2[i]) * kn; ku2[i] = f2bf(kh2);
            kdt[i]     = f2bf(kh1 * __expf(Le[i] - Lc[i]));
            kdt[i + 8] = f2bf(kh2 * __expf(Le[i + 8] - Lc[i + 8]));
        }
#pragma unroll
        for (int i = 0; i < 4; i++) {
            pk[i] = (unsigned)f2bf(bf2f(qu[2 * i]) * __expf(Lc[2 * i])) |
                    ((unsigned)f2bf(bf2f(qu[2 * i + 1]) * __expf(Lc[2 * i + 1])) << 16);
            pk[4 + i] = (unsigned)f2bf(bf2f(qu2[2 * i]) * __expf(Lc[8 + 2 * i])) |
                        ((unsigned)f2bf(bf2f(qu2[2 * i + 1]) * __expf(Lc[8 + 2 * i + 1])) << 16);
        }
        *(uint4*)&Qh[c * TP + qq * 16] = qa;
        *(uint4*)&Qh[c * TP + qq * 16 + 8] = qb;
        *(uint4*)&Kh[c * TP + qq * 16] = ka;
        *(uint4*)&Kh[c * TP + qq * 16 + 8] = kb;
        u16* qrow = &qdec[((size_t)bh * 4096 + ck * 64 + c) * 64 + qq * 16];
        *(uint4*)&qrow[0] = *(const uint4*)&pk[0];
        *(uint4*)&qrow[8] = *(const uint4*)&pk[4];
    }
    __syncthreads();

    u16* KDT = (u16*)L;
    {
        const int c = tid >> 2, qq = tid & 3;
#pragma unroll
        for (int i = 0; i < 16; i++) KDT[(qq * 16 + i) * TP + c] = kdt[i];
    }
    const int fr = l & 15;
    const int kk = (l >> 4) * 8;
    f32x4 accS[4] = {};
#pragma unroll
    for (int ks = 0; ks < 2; ks++) {
        s16x8 af = *(const s16x8*)&Qh[(w * 16 + fr) * TP + ks * 32 + kk];
#pragma unroll
        for (int j = 0; j < 4; j++) {
            s16x8 bf = *(const s16x8*)&Kh[(j * 16 + fr) * TP + ks * 32 + kk];
            accS[j] = MFMA16(af, bf, accS[j]);
        }
    }
    __syncthreads();

    {
        const int erow = w * 16 + (l >> 4) * 4;
#pragma unroll
        for (int j = 0; j < 4; j++) {
            const int mm = j * 16 + (l & 15);
            const float lmm = lm[mm];
#pragma unroll
            for (int r = 0; r < 4; r++) {
                const int cc = erow + r;
                const float wgt = (mm <= cc) ? __expf(lm[cc] - lmm) : 0.f;
                Qh[cc * TP + mm] = f2bf(accS[j][r] * wgt);
            }
        }
    }
    __syncthreads();

    f32x4 accO[4] = {};
    f32x4 accK[4] = {};
#pragma unroll
    for (int ks = 0; ks < 2; ks++) {
        s16x8 aAt = *(const s16x8*)&Qh[(w * 16 + fr) * TP + ks * 32 + kk];
        s16x8 aVt = *(const s16x8*)&VT[(w * 16 + fr) * TP + ks * 32 + kk];
#pragma unroll
        for (int j = 0; j < 4; j++) {
            s16x8 bVt = *(const s16x8*)&VT[(j * 16 + fr) * TP + ks * 32 + kk];
            s16x8 bKd = *(const s16x8*)&KDT[(j * 16 + fr) * TP + ks * 32 + kk];
            accO[j] = MFMA16(aAt, bVt, accO[j]);
            accK[j] = MFMA16(aVt, bKd, accK[j]);
        }
    }
    {
        const int erow = w * 16 + (l >> 4) * 4;
#pragma unroll
        for (int j = 0; j < 4; j++) {
            const int col = j * 16 + (l & 15);
#pragma unroll
            for (int r = 0; r < 4; r++) {
                const int row = erow + r;
                ointra[((size_t)bh * 4096 + ck * 64 + row) * 64 + col] = f2bf(accO[j][r]);
                kvT[(((size_t)bh * 64 + ck) * 64 + row) * 64 + col] = f2bf(accK[j][r]);
            }
        }
    }
}

// ---------------------------------------------------------------- elementwise chunk scan
__global__ __launch_bounds__(256) void gla_scan(
    const u16* __restrict__ kvT, const float* __restrict__ cdec,
    u16* __restrict__ ST)
{
    const int bh = blockIdx.x >> 4;
    const int de = (blockIdx.x & 15) * 256 + threadIdx.x;
    const int d = de & 63;
    float s = 0.f;
    const size_t base = (size_t)bh * 64 * 4096 + de;
    const size_t cb = (size_t)bh * 4096 + d;
    for (int t = 0; t < 64; t++) {
        ST[base + (size_t)t * 4096] = f2bf(s);
        s = s * cdec[cb + (size_t)t * 64] + bf2f(kvT[base + (size_t)t * 4096]);
    }
}

// ---------------------------------------------------------------- GLA phase B (MFMA)
__global__ __launch_bounds__(256) void gla_b(
    const u16* __restrict__ qdec, const u16* __restrict__ ST,
    const u16* __restrict__ ointra, u16* __restrict__ obf)
{
    __shared__ u16 Qd[64 * TP];
    __shared__ u16 Sd[64 * TP];
    const int bid = blockIdx.x;
    const int bh = bid >> 6, ck = bid & 63;
    const int b = bh >> 4, h = bh & 15;
    const int tid = threadIdx.x;
    const int w = tid >> 6, l = tid & 63;
#pragma unroll
    for (int pass = 0; pass < 2; pass++) {
        const int r = (tid >> 3) + pass * 32;
        const int col = (tid & 7) * 8;
        *(uint4*)&Qd[r * TP + col] =
            *(const uint4*)&qdec[((size_t)bh * 4096 + ck * 64 + r) * 64 + col];
        *(uint4*)&Sd[r * TP + col] =
            *(const uint4*)&ST[(((size_t)bh * 64 + ck) * 64 + r) * 64 + col];
    }
    __syncthreads();
    const int fr = l & 15;
    const int kk = (l >> 4) * 8;
    f32x4 acc[4] = {};
#pragma unroll
    for (int ks = 0; ks < 2; ks++) {
        s16x8 af = *(const s16x8*)&Qd[(w * 16 + fr) * TP + ks * 32 + kk];
#pragma unroll
        for (int j = 0; j < 4; j++) {
            s16x8 bf = *(const s16x8*)&Sd[(j * 16 + fr) * TP + ks * 32 + kk];
            acc[j] = MFMA16(af, bf, acc[j]);
        }
    }
    const int erow = w * 16 + (l >> 4) * 4;
#pragma unroll
    for (int j = 0; j < 4; j++) {
        const int e = j * 16 + (l & 15);
#pragma unroll
        for (int r = 0; r < 4; r++) {
            const int cc = erow + r;
            const size_t ia = ((size_t)bh * 4096 + ck * 64 + cc) * 64 + e;
            const float v = acc[j][r] + bf2f(ointra[ia]);
            obf[(size_t)(b * 4096 + ck * 64 + cc) * 1024 + h * 64 + e] = f2bf(v);
        }
    }
}

__global__ void fill_sentinel(float* out, int n) {
    int i = blockIdx.x * 256 + threadIdx.x;
    if (i < n) out[i] = 12345.0f;
}

// ---------------------------------------------------------------- host launcher
extern "C" void kernel_launch(void* const* d_in, const int* in_sizes, int n_in,
                              void* d_out, int out_size, void* d_ws, size_t ws_size,
                              hipStream_t stream)
{
    const float* x    = (const float*)d_in[0];
    const float* Wq   = (const float*)d_in[1];
    const float* Wk   = (const float*)d_in[2];
    const float* Wv   = (const float*)d_in[3];
    const float* Wg   = (const float*)d_in[4];
    const float* bg   = (const float*)d_in[5];
    const float* Wo   = (const float*)d_in[6];
    const float* ln1w = (const float*)d_in[7];
    const float* ln1b = (const float*)d_in[8];
    const float* ln2w = (const float*)d_in[9];
    const float* ln2b = (const float*)d_in[10];
    const float* W1   = (const float*)d_in[11];
    const float* b1   = (const float*)d_in[12];
    const float* W2   = (const float*)d_in[13];
    const float* b2   = (const float*)d_in[14];
    float* out = (float*)d_out;

    char* ws = (char*)d_ws;
    u16*   wtQKVG = (u16*)(ws + 0);            // 4096x1024 bf16
    u16*   wtWo   = (u16*)(ws + 8388608);      // 1024x1024
    u16*   wtW1   = (u16*)(ws + 10485760);     // 4096x1024
    u16*   wtW2   = (u16*)(ws + 18874368);     // 1024x4096
    u16*   xnb    = (u16*)(ws + 27262976);     // 8192x1024 bf16
    u16*   qkvb   = (u16*)(ws + 44040192);     // 8192x3072 bf16
    float* gbuf   = (float*)(ws + 94371840);   // 8192x1024 f32
    u16*   kvT    = (u16*)(ws + 127926272);    // 32x64x64x64 bf16
    float* cdbuf  = (float*)(ws + 144703488);  // 32x64x64 f32
    u16*   qdecb  = (u16*)(ws + 145227776);    // 32x4096x64 bf16
    u16*   ointra = (u16*)(ws + 162004992);    // 32x4096x64 bf16
    u16*   STb    = (u16*)(ws + 178782208);    // 32x64x64x64 bf16
    u16*   obf    = (u16*)(ws + 195559424);    // 8192x1024 bf16
    u16*   hbf    = (u16*)(ws + 212336640);    // 8192x1024 bf16
    float* x2     = (float*)(ws + 94371840);   // over gbuf (dead after gla_a)
    u16*   ffnb   = (u16*)(ws + 27262976);     // over xnb+qkvb (dead after gla_a)

    if (ws_size < 229113856u) {
        fill_sentinel<<<dim3((out_size + 255) / 256), dim3(256), 0, stream>>>(out, out_size);
        return;
    }

    const dim3 b256(256), b32x8(32, 8);

    transpose_all<<<dim3(13312), b32x8, 0, stream>>>(
        Wq, Wk, Wv, Wg, Wo, W1, W2, wtQKVG, wtWo, wtW1, wtW2);

    ln_bf16<<<dim3(8192), b256, 0, stream>>>(x, ln1w, ln1b, xnb);
    // fused q|k|v|gate GEMM: N=4096, epilogue splits bf16 qkv / f32 gate
    gemmL<0><<<dim3(64, 64), b256, 0, stream>>>(xnb, wtQKVG, gbuf, qkvb, nullptr, nullptr, 8192, 4096, 1024);

    gla_a<<<dim3(2048), b256, 0, stream>>>(qkvb, gbuf, bg, qdecb, kvT, cdbuf, ointra);
    gla_scan<<<dim3(512), b256, 0, stream>>>(kvT, cdbuf, STb);
    gla_b<<<dim3(2048), b256, 0, stream>>>(qdecb, STb, ointra, obf);

    gemmL<2><<<dim3(64, 16), b256, 0, stream>>>(obf, wtWo, x2, nullptr, nullptr, x, 8192, 1024, 1024);
    ln_bf16<<<dim3(8192), b256, 0, stream>>>(x2, ln2w, ln2b, hbf);
    gemmL<1><<<dim3(64, 64), b256, 0, stream>>>(hbf, wtW1, nullptr, ffnb, b1, nullptr, 8192, 4096, 1024);
    gemmL<4><<<dim3(64, 16), b256, 0, stream>>>(ffnb, wtW2, out, nullptr, b2, x2, 8192, 1024, 4096);
}